// Round 10
// baseline (109.680 us; speedup 1.0000x reference)
//
#include <hip/hip_runtime.h>
#include <hip/hip_bf16.h>

// Dims (fixed): B=64, R=5, N=512, A=64, U=128
typedef __attribute__((ext_vector_type(4))) float f32x4;
typedef __attribute__((ext_vector_type(8))) short s16x8;
typedef __attribute__((ext_vector_type(4))) short s16x4;

__device__ __forceinline__ unsigned short f2bf(float f) {
  __hip_bfloat16 h = __float2bfloat16(f);
  return __builtin_bit_cast(unsigned short, h);
}

#define AS1U(p) ((const __attribute__((address_space(1))) unsigned int*)(p))
#define AS3U(p) ((__attribute__((address_space(3))) unsigned int*)(p))

// ---- prep: blocks 0..511 transpose features -> FT; block 512 packs KT + bsum ----
// FT [64][64][512] bf16 ; KT [128][320] bf16 ; bsum[u] = sum_r bias[r][0][u]
__global__ void k_prep(const float* __restrict__ F, const float* __restrict__ K,
                       const float* __restrict__ bias,
                       unsigned short* __restrict__ FT, unsigned short* __restrict__ KT,
                       float* __restrict__ bsum) {
  if (blockIdx.x < 512) {
    __shared__ float t[64][65];
    const int b  = blockIdx.x >> 3;
    const int m0 = (blockIdx.x & 7) * 64;
    const int tid = threadIdx.x;  // 256
    {
      const int row = tid >> 2, ac = (tid & 3) * 16;
      const float* src = F + ((size_t)b * 512 + m0 + row) * 64 + ac;
      #pragma unroll
      for (int j = 0; j < 4; ++j) {
        f32x4 v = *(const f32x4*)(src + j * 4);
        t[row][ac + j * 4 + 0] = v[0]; t[row][ac + j * 4 + 1] = v[1];
        t[row][ac + j * 4 + 2] = v[2]; t[row][ac + j * 4 + 3] = v[3];
      }
    }
    __syncthreads();
    {
      const int a = tid >> 2, mc = (tid & 3) * 16;
      unsigned short* dst = FT + ((size_t)b * 64 + a) * 512 + m0 + mc;
      s16x8 p0, p1;
      #pragma unroll
      for (int j = 0; j < 8; ++j) {
        p0[j] = (short)f2bf(t[mc + j][a]);
        p1[j] = (short)f2bf(t[mc + 8 + j][a]);
      }
      *(s16x8*)(dst) = p0;
      *(s16x8*)(dst + 8) = p1;
    }
  } else {
    const int tid = threadIdx.x;
    for (int idx = tid; idx < 128 * 320; idx += 256) {
      const int u = idx / 320, ra = idx % 320;         // ra = r*64 + a
      KT[idx] = f2bf(K[(size_t)ra * 128 + u]);
    }
    if (tid < 128) {
      float s = 0.f;
      #pragma unroll
      for (int r = 0; r < 5; ++r) s += bias[r * 128 + tid];
      bsum[tid] = s;
    }
  }
}

// ---- Fused v9 = r9 (v8b) body unchanged + bijective XCD-aware block swizzle.
// global_load_lds (DMA) adjacency ingress; per-wave double-buffered f32 queue
// [2][16][128]; DMA writes linear, read side XOR-swizzled by ((row&7)<<4) B
// with the inverse pre-applied to the global source (both-sides involution).
// Counted vmcnt(8) keeps the next stage's 8 DMAs in flight. Barrier-free.
__global__ __launch_bounds__(256, 2) void k_fused(const float* __restrict__ Adj,
                                                  const unsigned short* __restrict__ FT,
                                                  const unsigned short* __restrict__ KT,
                                                  const float* __restrict__ bsum,
                                                  float* __restrict__ out) {
  __shared__ __align__(16) float shq[4][2][16][128];   // 64 KB; wave stride 4096 f, buffer stride 2048 f
  const int bi = blockIdx.x;
  const int L  = (bi & 7) * 64 + (bi >> 3);   // XCD k owns batches 8k..8k+7 (512 = 8*64, bijective)
  const int b  = L >> 3;
  const int nt = L & 7;
  const int w  = threadIdx.x >> 6;
  const int l  = threadIdx.x & 63;
  const int l15 = l & 15, g = l >> 4;

  const float* adjW = Adj + (size_t)b * 5 * 262144 + (size_t)(nt * 64 + w * 16) * 512;
  const unsigned short* ftW = FT + (size_t)b * 64 * 512;
  const int srow = l >> 5;            // row within the call's row-pair
  const int c16  = (l & 31) * 16;     // linear dest byte within the 512B row-chunk

  float* qw = &shq[w][0][0][0];

  // prologue: DMAs for stage 0 (r=0, kc=0) into buffer 0
  #pragma unroll
  for (int i = 0; i < 8; ++i) {
    const int xr = (2 * i) & 7;
    const float* src = adjW + (size_t)(2 * i + srow) * 512 + ((c16 ^ ((xr + srow) << 4)) >> 2);
    __builtin_amdgcn_global_load_lds(AS1U(src), AS3U(qw + i * 256), 16, 0, 0);
  }

  f32x4 acc[5][4];
  #pragma unroll
  for (int r = 0; r < 5; ++r)
    #pragma unroll
    for (int at = 0; at < 4; ++at) acc[r][at] = (f32x4)0.f;

  #pragma unroll
  for (int ks4 = 0; ks4 < 4; ++ks4) {
    // FT frags for this 128-col K-chunk, reused across all 5 relations
    s16x8 ffrag[4][4];
    #pragma unroll
    for (int ksl = 0; ksl < 4; ++ksl)
      #pragma unroll
      for (int at = 0; at < 4; ++at)
        ffrag[ksl][at] = *(const s16x8*)(ftW + (size_t)(at * 16 + l15) * 512 + ks4 * 128 + ksl * 32 + g * 8);

    #pragma unroll
    for (int r = 0; r < 5; ++r) {
      const int s = ks4 * 5 + r;
      const int cur = s & 1;
      const bool have_next = (s < 19);
      if (have_next) {
        const int rn = (r == 4) ? 0 : r + 1;
        const int kn = (r == 4) ? ks4 + 1 : ks4;
        const float* sb = adjW + (size_t)rn * 262144 + kn * 128;
        #pragma unroll
        for (int i = 0; i < 8; ++i) {
          const int xr = (2 * i) & 7;
          const float* src = sb + (size_t)(2 * i + srow) * 512 + ((c16 ^ ((xr + srow) << 4)) >> 2);
          __builtin_amdgcn_global_load_lds(AS1U(src), AS3U(qw + (cur ^ 1) * 2048 + i * 256), 16, 0, 0);
        }
        asm volatile("s_waitcnt vmcnt(8)" ::: "memory");   // stage-s DMAs drained; next 8 in flight
      } else {
        asm volatile("s_waitcnt vmcnt(0)" ::: "memory");
      }
      __builtin_amdgcn_sched_barrier(0);

      const char* qr = (const char*)(qw + cur * 2048 + l15 * 128);
      const int x = (l15 & 7) << 4;
      #pragma unroll
      for (int ksl = 0; ksl < 4; ++ksl) {
        const int C = ksl * 128 + g * 32;
        f32x4 lo = *(const f32x4*)(qr + (C ^ x));
        f32x4 hi = *(const f32x4*)(qr + ((C + 16) ^ x));
        s16x8 bfrag;
        #pragma unroll
        for (int j = 0; j < 4; ++j) {
          bfrag[j]     = (short)f2bf(lo[j]);
          bfrag[4 + j] = (short)f2bf(hi[j]);
        }
        acc[r][0] = __builtin_amdgcn_mfma_f32_16x16x32_bf16(ffrag[ksl][0], bfrag, acc[r][0], 0, 0, 0);
        acc[r][1] = __builtin_amdgcn_mfma_f32_16x16x32_bf16(ffrag[ksl][1], bfrag, acc[r][1], 0, 0, 0);
        acc[r][2] = __builtin_amdgcn_mfma_f32_16x16x32_bf16(ffrag[ksl][2], bfrag, acc[r][2], 0, 0, 0);
        acc[r][3] = __builtin_amdgcn_mfma_f32_16x16x32_bf16(ffrag[ksl][3], bfrag, acc[r][3], 0, 0, 0);
      }
    }
  }

  // phase 2: ag tile overlays this wave's queue region (all DMA/reads drained above)
  unsigned short* agw = (unsigned short*)qw;   // [16][328] u16, 10.5 KB < 16 KB
  #pragma unroll
  for (int r = 0; r < 5; ++r)
    #pragma unroll
    for (int at = 0; at < 4; ++at) {
      s16x4 pk;
      pk[0] = (short)f2bf(acc[r][at][0]); pk[1] = (short)f2bf(acc[r][at][1]);
      pk[2] = (short)f2bf(acc[r][at][2]); pk[3] = (short)f2bf(acc[r][at][3]);
      *(s16x4*)&agw[l15 * 328 + r * 64 + at * 16 + g * 4] = pk;
    }
  // no barrier: per-wave region, in-wave DS ordering

  // phase 3: out-GEMM K=320, A from own ag tile, B = KT (L2-resident)
  f32x4 o[8];
  #pragma unroll
  for (int ut = 0; ut < 8; ++ut) o[ut] = (f32x4)0.f;

  #pragma unroll 2
  for (int ks = 0; ks < 10; ++ks) {
    s16x8 af = *(const s16x8*)&agw[l15 * 328 + ks * 32 + g * 8];
    #pragma unroll
    for (int ut = 0; ut < 8; ++ut) {
      s16x8 kf = *(const s16x8*)(KT + (size_t)(ut * 16 + l15) * 320 + ks * 32 + g * 8);
      o[ut] = __builtin_amdgcn_mfma_f32_16x16x32_bf16(af, kf, o[ut], 0, 0, 0);
    }
  }

  // epilogue: D2 col=l15 -> u, row=g*4+t -> n
  #pragma unroll
  for (int ut = 0; ut < 8; ++ut) {
    const int u = ut * 16 + l15;
    const float bs = bsum[u];
    float* op = out + ((size_t)b * 512 + nt * 64 + w * 16 + g * 4) * 128 + u;
    #pragma unroll
    for (int t = 0; t < 4; ++t) {
      float vv = o[ut][t] + bs;
      op[(size_t)t * 128] = vv > 0.f ? vv : 0.f;
    }
  }
}

extern "C" void kernel_launch(void* const* d_in, const int* in_sizes, int n_in,
                              void* d_out, int out_size, void* d_ws, size_t ws_size,
                              hipStream_t stream) {
  const float* adj  = (const float*)d_in[0];   // [64][5][512][512]
  const float* feat = (const float*)d_in[1];   // [64][512][64]
  const float* kern = (const float*)d_in[2];   // [5][64][128]
  const float* bias = (const float*)d_in[3];   // [5][1][128]
  float* out = (float*)d_out;                  // [64][512][128] f32

  char* ws = (char*)d_ws;
  unsigned short* FT   = (unsigned short*)ws;                  // 64*64*512*2 = 4,194,304 B
  unsigned short* KT   = (unsigned short*)(ws + 4194304);      // 128*320*2   =    81,920 B
  float*          bsum = (float*)(ws + 4194304 + 81920);       // 128*4       =       512 B

  hipLaunchKernelGGL(k_prep,  dim3(513), dim3(256), 0, stream, feat, kern, bias, FT, KT, bsum);
  hipLaunchKernelGGL(k_fused, dim3(512), dim3(256), 0, stream, adj, FT, KT, bsum, out);
  (void)in_sizes; (void)n_in; (void)out_size; (void)ws_size;
}

// Round 11
// 88.599 us; speedup vs baseline: 1.2379x; 1.2379x over previous
//
#include <hip/hip_runtime.h>
#include <hip/hip_bf16.h>

// Dims (fixed): B=64, R=5, N=512, A=64, U=128
typedef __attribute__((ext_vector_type(4))) float f32x4;
typedef __attribute__((ext_vector_type(8))) short s16x8;
typedef __attribute__((ext_vector_type(4))) short s16x4;

__device__ __forceinline__ unsigned short f2bf(float f) {
  __hip_bfloat16 h = __float2bfloat16(f);
  return __builtin_bit_cast(unsigned short, h);
}

#define AS1U(p) ((const __attribute__((address_space(1))) unsigned int*)(p))
#define AS3U(p) ((__attribute__((address_space(3))) unsigned int*)(p))

// ---- prep (512 blocks): per-block feature-transpose tile -> FT, PLUS a
// distributed 80-element slice of the KT pack (40960 = 512*80, no straggler);
// block 0 also computes bsum. One launch replaces k_ft + k_kt.
__global__ void k_prep(const float* __restrict__ F, const float* __restrict__ K,
                       const float* __restrict__ bias,
                       unsigned short* __restrict__ FT, unsigned short* __restrict__ KT,
                       float* __restrict__ bsum) {
  __shared__ float t[64][65];
  const int b  = blockIdx.x >> 3;
  const int m0 = (blockIdx.x & 7) * 64;
  const int tid = threadIdx.x;  // 256
  {
    const int row = tid >> 2, ac = (tid & 3) * 16;
    const float* src = F + ((size_t)b * 512 + m0 + row) * 64 + ac;
    #pragma unroll
    for (int j = 0; j < 4; ++j) {
      f32x4 v = *(const f32x4*)(src + j * 4);
      t[row][ac + j * 4 + 0] = v[0]; t[row][ac + j * 4 + 1] = v[1];
      t[row][ac + j * 4 + 2] = v[2]; t[row][ac + j * 4 + 3] = v[3];
    }
  }
  // KT slice: 80 elements per block, one overlapped latency round
  if (tid < 80) {
    const int idx = blockIdx.x * 80 + tid;
    const int u = idx / 320, ra = idx % 320;           // ra = r*64 + a
    KT[idx] = f2bf(K[(size_t)ra * 128 + u]);
  }
  if (blockIdx.x == 0 && tid >= 128 && tid < 256) {
    const int u = tid - 128;
    float s = 0.f;
    #pragma unroll
    for (int r = 0; r < 5; ++r) s += bias[r * 128 + u];
    bsum[u] = s;
  }
  __syncthreads();
  {
    const int a = tid >> 2, mc = (tid & 3) * 16;
    unsigned short* dst = FT + ((size_t)b * 64 + a) * 512 + m0 + mc;
    s16x8 p0, p1;
    #pragma unroll
    for (int j = 0; j < 8; ++j) {
      p0[j] = (short)f2bf(t[mc + j][a]);
      p1[j] = (short)f2bf(t[mc + 8 + j][a]);
    }
    *(s16x8*)(dst) = p0;
    *(s16x8*)(dst + 8) = p1;
  }
}

// ---- Fused v8b (r9 verbatim, best: 92.8 us): global_load_lds (DMA) adjacency
// ingress; per-wave double-buffered f32 queue [2][16][128]; DMA writes linear,
// read side XOR-swizzled by ((row&7)<<4) B with the inverse pre-applied to the
// global source (both-sides involution). Counted vmcnt(8) keeps the next
// stage's 8 DMAs in flight. Barrier-free (per-wave regions).
__global__ __launch_bounds__(256, 2) void k_fused(const float* __restrict__ Adj,
                                                  const unsigned short* __restrict__ FT,
                                                  const unsigned short* __restrict__ KT,
                                                  const float* __restrict__ bsum,
                                                  float* __restrict__ out) {
  __shared__ __align__(16) float shq[4][2][16][128];   // 64 KB; wave stride 4096 f, buffer stride 2048 f
  const int b  = blockIdx.x >> 3;
  const int nt = blockIdx.x & 7;
  const int w  = threadIdx.x >> 6;
  const int l  = threadIdx.x & 63;
  const int l15 = l & 15, g = l >> 4;

  const float* adjW = Adj + (size_t)b * 5 * 262144 + (size_t)(nt * 64 + w * 16) * 512;
  const unsigned short* ftW = FT + (size_t)b * 64 * 512;
  const int srow = l >> 5;            // row within the call's row-pair
  const int c16  = (l & 31) * 16;     // linear dest byte within the 512B row-chunk

  float* qw = &shq[w][0][0][0];

  // prologue: DMAs for stage 0 (r=0, kc=0) into buffer 0
  #pragma unroll
  for (int i = 0; i < 8; ++i) {
    const int xr = (2 * i) & 7;
    const float* src = adjW + (size_t)(2 * i + srow) * 512 + ((c16 ^ ((xr + srow) << 4)) >> 2);
    __builtin_amdgcn_global_load_lds(AS1U(src), AS3U(qw + i * 256), 16, 0, 0);
  }

  f32x4 acc[5][4];
  #pragma unroll
  for (int r = 0; r < 5; ++r)
    #pragma unroll
    for (int at = 0; at < 4; ++at) acc[r][at] = (f32x4)0.f;

  #pragma unroll
  for (int ks4 = 0; ks4 < 4; ++ks4) {
    // FT frags for this 128-col K-chunk, reused across all 5 relations
    s16x8 ffrag[4][4];
    #pragma unroll
    for (int ksl = 0; ksl < 4; ++ksl)
      #pragma unroll
      for (int at = 0; at < 4; ++at)
        ffrag[ksl][at] = *(const s16x8*)(ftW + (size_t)(at * 16 + l15) * 512 + ks4 * 128 + ksl * 32 + g * 8);

    #pragma unroll
    for (int r = 0; r < 5; ++r) {
      const int s = ks4 * 5 + r;
      const int cur = s & 1;
      const bool have_next = (s < 19);
      if (have_next) {
        const int rn = (r == 4) ? 0 : r + 1;
        const int kn = (r == 4) ? ks4 + 1 : ks4;
        const float* sb = adjW + (size_t)rn * 262144 + kn * 128;
        #pragma unroll
        for (int i = 0; i < 8; ++i) {
          const int xr = (2 * i) & 7;
          const float* src = sb + (size_t)(2 * i + srow) * 512 + ((c16 ^ ((xr + srow) << 4)) >> 2);
          __builtin_amdgcn_global_load_lds(AS1U(src), AS3U(qw + (cur ^ 1) * 2048 + i * 256), 16, 0, 0);
        }
        asm volatile("s_waitcnt vmcnt(8)" ::: "memory");   // stage-s DMAs drained; next 8 in flight
      } else {
        asm volatile("s_waitcnt vmcnt(0)" ::: "memory");
      }
      __builtin_amdgcn_sched_barrier(0);

      const char* qr = (const char*)(qw + cur * 2048 + l15 * 128);
      const int x = (l15 & 7) << 4;
      #pragma unroll
      for (int ksl = 0; ksl < 4; ++ksl) {
        const int C = ksl * 128 + g * 32;
        f32x4 lo = *(const f32x4*)(qr + (C ^ x));
        f32x4 hi = *(const f32x4*)(qr + ((C + 16) ^ x));
        s16x8 bfrag;
        #pragma unroll
        for (int j = 0; j < 4; ++j) {
          bfrag[j]     = (short)f2bf(lo[j]);
          bfrag[4 + j] = (short)f2bf(hi[j]);
        }
        acc[r][0] = __builtin_amdgcn_mfma_f32_16x16x32_bf16(ffrag[ksl][0], bfrag, acc[r][0], 0, 0, 0);
        acc[r][1] = __builtin_amdgcn_mfma_f32_16x16x32_bf16(ffrag[ksl][1], bfrag, acc[r][1], 0, 0, 0);
        acc[r][2] = __builtin_amdgcn_mfma_f32_16x16x32_bf16(ffrag[ksl][2], bfrag, acc[r][2], 0, 0, 0);
        acc[r][3] = __builtin_amdgcn_mfma_f32_16x16x32_bf16(ffrag[ksl][3], bfrag, acc[r][3], 0, 0, 0);
      }
    }
  }

  // phase 2: ag tile overlays this wave's queue region (all DMA/reads drained above)
  unsigned short* agw = (unsigned short*)qw;   // [16][328] u16, 10.5 KB < 16 KB
  #pragma unroll
  for (int r = 0; r < 5; ++r)
    #pragma unroll
    for (int at = 0; at < 4; ++at) {
      s16x4 pk;
      pk[0] = (short)f2bf(acc[r][at][0]); pk[1] = (short)f2bf(acc[r][at][1]);
      pk[2] = (short)f2bf(acc[r][at][2]); pk[3] = (short)f2bf(acc[r][at][3]);
      *(s16x4*)&agw[l15 * 328 + r * 64 + at * 16 + g * 4] = pk;
    }
  // no barrier: per-wave region, in-wave DS ordering

  // phase 3: out-GEMM K=320, A from own ag tile, B = KT (L2-resident)
  f32x4 o[8];
  #pragma unroll
  for (int ut = 0; ut < 8; ++ut) o[ut] = (f32x4)0.f;

  #pragma unroll 2
  for (int ks = 0; ks < 10; ++ks) {
    s16x8 af = *(const s16x8*)&agw[l15 * 328 + ks * 32 + g * 8];
    #pragma unroll
    for (int ut = 0; ut < 8; ++ut) {
      s16x8 kf = *(const s16x8*)(KT + (size_t)(ut * 16 + l15) * 320 + ks * 32 + g * 8);
      o[ut] = __builtin_amdgcn_mfma_f32_16x16x32_bf16(af, kf, o[ut], 0, 0, 0);
    }
  }

  // epilogue: D2 col=l15 -> u, row=g*4+t -> n
  #pragma unroll
  for (int ut = 0; ut < 8; ++ut) {
    const int u = ut * 16 + l15;
    const float bs = bsum[u];
    float* op = out + ((size_t)b * 512 + nt * 64 + w * 16 + g * 4) * 128 + u;
    #pragma unroll
    for (int t = 0; t < 4; ++t) {
      float vv = o[ut][t] + bs;
      op[(size_t)t * 128] = vv > 0.f ? vv : 0.f;
    }
  }
}

extern "C" void kernel_launch(void* const* d_in, const int* in_sizes, int n_in,
                              void* d_out, int out_size, void* d_ws, size_t ws_size,
                              hipStream_t stream) {
  const float* adj  = (const float*)d_in[0];   // [64][5][512][512]
  const float* feat = (const float*)d_in[1];   // [64][512][64]
  const float* kern = (const float*)d_in[2];   // [5][64][128]
  const float* bias = (const float*)d_in[3];   // [5][1][128]
  float* out = (float*)d_out;                  // [64][512][128] f32

  char* ws = (char*)d_ws;
  unsigned short* FT   = (unsigned short*)ws;                  // 64*64*512*2 = 4,194,304 B
  unsigned short* KT   = (unsigned short*)(ws + 4194304);      // 128*320*2   =    81,920 B
  float*          bsum = (float*)(ws + 4194304 + 81920);       // 128*4       =       512 B

  hipLaunchKernelGGL(k_prep,  dim3(512), dim3(256), 0, stream, feat, kern, bias, FT, KT, bsum);
  hipLaunchKernelGGL(k_fused, dim3(512), dim3(256), 0, stream, adj, FT, KT, bsum, out);
  (void)in_sizes; (void)n_in; (void)out_size; (void)ws_size;
}